// Round 4
// baseline (420.337 us; speedup 1.0000x reference)
//
#include <hip/hip_runtime.h>

typedef __bf16 bf16x8 __attribute__((ext_vector_type(8)));
typedef float  f32x4  __attribute__((ext_vector_type(4)));

constexpr int M_ROWS = 65536;
constexpr int N_COLS = 2048;
constexpr int K_DIM  = 512;
constexpr int BM = 128, BN = 128, BK = 32;
constexpr int NKT = K_DIM / BK;        // 16 K-steps
constexpr int MB_CNT = M_ROWS / BM;    // 512
constexpr int NB_CNT = N_COLS / BN;    // 16

constexpr size_t A_ELEMS = (size_t)M_ROWS * K_DIM;
constexpr size_t W_ELEMS = (size_t)N_COLS * K_DIM;
// packed blocks: per (tile, kt): [hi 4096 ushorts][lo 4096 ushorts] = 16 KB
constexpr size_t APK_USHORTS = (size_t)MB_CNT * NKT * 8192;  // 128 MiB
constexpr size_t WPK_USHORTS = (size_t)NB_CNT * NKT * 8192;  //   4 MiB

__device__ __forceinline__ unsigned short f2bf(float f){
  unsigned int u = __float_as_uint(f);
  u += 0x7FFFu + ((u >> 16) & 1u);     // RNE
  return (unsigned short)(u >> 16);
}
__device__ __forceinline__ float bf2f(unsigned short h){
  return __uint_as_float(((unsigned int)h) << 16);
}
__device__ __forceinline__ void split4(const float4& v, ushort4& h, ushort4& l){
  h.x = f2bf(v.x); l.x = f2bf(v.x - bf2f(h.x));
  h.y = f2bf(v.y); l.y = f2bf(v.y - bf2f(h.y));
  h.z = f2bf(v.z); l.z = f2bf(v.z - bf2f(h.z));
  h.w = f2bf(v.w); l.w = f2bf(v.w - bf2f(h.w));
}

__device__ __forceinline__ void gl_lds16(const void* g, void* l){
  __builtin_amdgcn_global_load_lds(
      (const __attribute__((address_space(1))) unsigned int*)g,
      (__attribute__((address_space(3))) unsigned int*)l, 16, 0, 0);
}

constexpr float INV2PI = 0.15915494309189535f;
__device__ __forceinline__ float cos_scaled(float v){
  float rev = v * INV2PI;
  rev -= floorf(rev);                   // [0,1) revolutions for v_cos
  return 0.03125f * __builtin_amdgcn_cosf(rev);
}

// ---------------- prepass: X -> Apk (fragment-linear, hi/lo split) ----------
// Apk block (mb,kt): chunk c = i*64 + q*16 + r  <->  A row mb*128+i*16+r,
// k = kt*32 + q*8 .. +7 (bf16, k-contiguous). hi at +0, lo at +4096 ushorts.
__global__ void pack_x(const float* __restrict__ X, unsigned short* __restrict__ Apk){
  __shared__ __align__(16) unsigned short lds[8192];
  const int mb = blockIdx.x, kt = blockIdx.y, t = threadIdx.x;
  const float* src = X + (size_t)mb * 128 * K_DIM + kt * 32;
  const int fq = t & 7, r0 = t >> 3;
  #pragma unroll
  for (int it = 0; it < 4; ++it){
    int row = r0 + it * 32;
    float4 v = *reinterpret_cast<const float4*>(src + (size_t)row * K_DIM + fq * 4);
    ushort4 h, l; split4(v, h, l);
    int i = row >> 4, r = row & 15, q = fq >> 1, half = fq & 1;
    int base = (i * 64 + q * 16 + r) * 8 + half * 4;
    *reinterpret_cast<ushort4*>(lds + base)        = h;
    *reinterpret_cast<ushort4*>(lds + 4096 + base) = l;
  }
  __syncthreads();
  unsigned short* dst = Apk + ((size_t)mb * NKT + kt) * 8192;
  #pragma unroll
  for (int it = 0; it < 4; ++it){
    int c = t + it * 256;
    *reinterpret_cast<int4*>(dst + c * 8) = *reinterpret_cast<const int4*>(lds + c * 8);
  }
}

// ---------------- prepass: W -> Wpk (transpose + fragment-linear + col-perm) -
// Wpk block (nb,kt): chunk c = s*64 + q*16 + fc holds W[k=kt*32+q*8..][n],
// n = nb*128 + (s>>2)*64 + fc*4 + (s&3)  -- column permutation so the
// epilogue writes contiguous float4 per lane.
__global__ void pack_w(const float* __restrict__ W, unsigned short* __restrict__ Wpk){
  __shared__ __align__(16) unsigned short lds[8192];
  const int nb = blockIdx.x, kt = blockIdx.y, t = threadIdx.x;
  const int nq = t & 31, kr0 = t >> 5;
  #pragma unroll
  for (int it = 0; it < 4; ++it){
    int kr = kr0 + it * 8;
    float4 v = *reinterpret_cast<const float4*>(
        W + (size_t)(kt * 32 + kr) * N_COLS + nb * 128 + nq * 4);
    float vv[4] = {v.x, v.y, v.z, v.w};
    int q = kr >> 3, ko = kr & 7;
    #pragma unroll
    for (int c = 0; c < 4; ++c){
      int nl = nq * 4 + c;
      int s  = ((nl >> 6) << 2) + (nl & 3);
      int fc = (nl >> 2) & 15;
      unsigned short h = f2bf(vv[c]);
      unsigned short l = f2bf(vv[c] - bf2f(h));
      int e = (s * 64 + q * 16 + fc) * 8 + ko;
      lds[e] = h; lds[4096 + e] = l;
    }
  }
  __syncthreads();
  unsigned short* dst = Wpk + ((size_t)nb * NKT + kt) * 8192;
  #pragma unroll
  for (int it = 0; it < 4; ++it){
    int c = t + it * 256;
    *reinterpret_cast<int4*>(dst + c * 8) = *reinterpret_cast<const int4*>(lds + c * 8);
  }
}

// ---------------- main GEMM + cos epilogue (packed, double-buffered) --------
__launch_bounds__(256, 2)
__global__ void rbf_gemm_pk(const unsigned short* __restrict__ Apk,
                            const unsigned short* __restrict__ Wpk,
                            const float* __restrict__ bvec,
                            float* __restrict__ out){
  // 2 buffers x 32 KB: [A hi 8K][A lo 8K][B hi 8K][B lo 8K] bytes each,
  // fragment-linear (chunk l = lane l's 16B fragment)
  __shared__ __align__(16) unsigned short smem[2 * 16384];

  int orig = blockIdx.x;                       // 8192 blocks, 8192 % 8 == 0
  int wgid = (orig & 7) * 1024 + (orig >> 3);  // bijective XCD swizzle
  int mb = wgid >> 4, nb = wgid & 15;
  int m0 = mb * BM, n0 = nb * BN;

  int tid = threadIdx.x, lane = tid & 63, wid = tid >> 6;
  int wm = wid >> 1, wn = wid & 1;
  int r = lane & 15, g = lane >> 4;

  const char* asrc = (const char*)(Apk + (size_t)mb * NKT * 8192) + tid * 16;
  const char* bsrc = (const char*)(Wpk + (size_t)nb * NKT * 8192) + tid * 16;
  char* ldsb = (char*)smem;
  const int ldst = wid * 1024;                 // per-wave dest offset in each 4KB sec

  f32x4 acc[4][4];
  f32x4 zero = {0.f, 0.f, 0.f, 0.f};
  #pragma unroll
  for (int i = 0; i < 4; ++i)
    #pragma unroll
    for (int j = 0; j < 4; ++j) acc[i][j] = zero;

  const int lbase = lane * 8;                  // ushort offset of lane's chunk

  // prologue: stage tile 0 into buffer 0
  #pragma unroll
  for (int it = 0; it < 4; ++it)
    gl_lds16(asrc + it * 4096, ldsb + it * 4096 + ldst);
  #pragma unroll
  for (int it = 0; it < 4; ++it)
    gl_lds16(bsrc + it * 4096, ldsb + 16384 + it * 4096 + ldst);
  __syncthreads();                             // drain vmcnt(0): tile 0 ready

  #pragma unroll 1
  for (int kt = 0; kt < NKT; ++kt){
    const unsigned short* S = smem + ((kt & 1) << 14);   // current buffer (ushorts)

    // 1) ds_read current-tile fragments
    bf16x8 ah[4], al[4], bh[4], bl[4];
    #pragma unroll
    for (int i = 0; i < 4; ++i){
      int o = (wm * 4 + i) * 512 + lbase;
      ah[i] = *reinterpret_cast<const bf16x8*>(&S[o]);
      al[i] = *reinterpret_cast<const bf16x8*>(&S[o + 4096]);
    }
    #pragma unroll
    for (int j = 0; j < 4; ++j){
      int o = 8192 + (wn * 4 + j) * 512 + lbase;
      bh[j] = *reinterpret_cast<const bf16x8*>(&S[o]);
      bl[j] = *reinterpret_cast<const bf16x8*>(&S[o + 4096]);
    }

    // 2) issue next-tile gl_lds into the other buffer (in flight across MFMA)
    if (kt + 1 < NKT){
      char* L = ldsb + (((kt + 1) & 1) << 15) + ldst;
      const char* ab = asrc + (size_t)(kt + 1) * 16384;
      const char* bb = bsrc + (size_t)(kt + 1) * 16384;
      #pragma unroll
      for (int it = 0; it < 4; ++it) gl_lds16(ab + it * 4096, L + it * 4096);
      #pragma unroll
      for (int it = 0; it < 4; ++it) gl_lds16(bb + it * 4096, L + 16384 + it * 4096);
    }

    // 3) MFMA cluster (hides the loads)
    #pragma unroll
    for (int i = 0; i < 4; ++i){
      #pragma unroll
      for (int j = 0; j < 4; ++j){
        acc[i][j] = __builtin_amdgcn_mfma_f32_16x16x32_bf16(ah[i], bh[j], acc[i][j], 0, 0, 0);
        acc[i][j] = __builtin_amdgcn_mfma_f32_16x16x32_bf16(al[i], bh[j], acc[i][j], 0, 0, 0);
        acc[i][j] = __builtin_amdgcn_mfma_f32_16x16x32_bf16(ah[i], bl[j], acc[i][j], 0, 0, 0);
      }
    }

    __syncthreads();   // one barrier/step: next tile landed, all reads done
  }

  // epilogue: col for acc[i][j] lane(r,g) reg p = n0 + wn*64 + r*4 + j
  //           row = m0 + wm*64 + i*16 + g*4 + p  -> nontemporal f32x4 stores
  int colb = n0 + wn * 64 + r * 4;
  float4 bv4 = *reinterpret_cast<const float4*>(bvec + colb);
  #pragma unroll
  for (int i = 0; i < 4; ++i){
    #pragma unroll
    for (int p = 0; p < 4; ++p){
      int row = m0 + wm * 64 + i * 16 + g * 4 + p;
      f32x4 o;
      o.x = cos_scaled(acc[i][0][p] + bv4.x);
      o.y = cos_scaled(acc[i][1][p] + bv4.y);
      o.z = cos_scaled(acc[i][2][p] + bv4.z);
      o.w = cos_scaled(acc[i][3][p] + bv4.w);
      __builtin_nontemporal_store(o, reinterpret_cast<f32x4*>(out + (size_t)row * N_COLS + colb));
    }
  }
}

// ---------------- fallback (no workspace) -----------------------------------
constexpr int LDSK = 40;
constexpr int SEC  = 128 * LDSK;
__launch_bounds__(256, 2)
__global__ void rbf_gemm_nows(const float* __restrict__ X, const float* __restrict__ W,
                              const float* __restrict__ bvec, float* __restrict__ out){
  __shared__ __align__(16) unsigned short smem[4 * SEC];
  int orig = blockIdx.x;
  int wgid = (orig & 7) * (int)(gridDim.x >> 3) + (orig >> 3);
  int mb = wgid >> 4, nb = wgid & 15;
  int m0 = mb * BM, n0 = nb * BN;
  int tid = threadIdx.x, lane = tid & 63, wid = tid >> 6;
  int wm = wid >> 1, wn = wid & 1;
  int r = lane & 15, g = lane >> 4;

  const float* asrc[4]; int alofs[4]; float4 ra[4];
  const float* wsrc[4]; int wnq4[4]; int wkr[4]; float4 rw[4];
  #pragma unroll
  for (int i = 0; i < 4; ++i){
    int c = tid + i * 256;
    int row = c >> 3, q = c & 7;
    asrc[i]  = X + (size_t)(m0 + row) * K_DIM + q * 4;
    alofs[i] = row * LDSK + q * 4;
  }
  #pragma unroll
  for (int i = 0; i < 4; ++i) ra[i] = *reinterpret_cast<const float4*>(asrc[i]);
  #pragma unroll
  for (int i = 0; i < 4; ++i){
    int c = tid + i * 256;
    int kr = c >> 5, nq = c & 31;
    wsrc[i] = W + (size_t)kr * N_COLS + n0 + nq * 4;
    wkr[i] = kr; wnq4[i] = nq * 4;
  }
  #pragma unroll
  for (int i = 0; i < 4; ++i) rw[i] = *reinterpret_cast<const float4*>(wsrc[i]);

  f32x4 acc[4][4];
  f32x4 zero = {0.f, 0.f, 0.f, 0.f};
  #pragma unroll
  for (int i = 0; i < 4; ++i)
    #pragma unroll
    for (int j = 0; j < 4; ++j) acc[i][j] = zero;

  int aoff[4], boff[4];
  #pragma unroll
  for (int i = 0; i < 4; ++i) aoff[i] = (wm*64 + i*16 + r) * LDSK + g * 8;
  #pragma unroll
  for (int j = 0; j < 4; ++j) boff[j] = (wn*64 + j*16 + r) * LDSK + g * 8;

  #pragma unroll 1
  for (int kt = 0; kt < NKT; ++kt){
    __syncthreads();
    #pragma unroll
    for (int i = 0; i < 4; ++i){
      ushort4 h, l;
      split4(ra[i], h, l);
      *reinterpret_cast<ushort4*>(&smem[alofs[i]])       = h;
      *reinterpret_cast<ushort4*>(&smem[SEC + alofs[i]]) = l;
    }
    #pragma unroll
    for (int i = 0; i < 4; ++i){
      float vv[4] = {rw[i].x, rw[i].y, rw[i].z, rw[i].w};
      #pragma unroll
      for (int w2 = 0; w2 < 4; ++w2){
        unsigned short h = f2bf(vv[w2]);
        unsigned short l = f2bf(vv[w2] - bf2f(h));
        int n = wnq4[i] + w2;
        smem[2*SEC + n*LDSK + wkr[i]] = h;
        smem[3*SEC + n*LDSK + wkr[i]] = l;
      }
    }
    if (kt < NKT - 1){
      #pragma unroll
      for (int i = 0; i < 4; ++i)
        ra[i] = *reinterpret_cast<const float4*>(asrc[i] + (kt+1)*BK);
      #pragma unroll
      for (int i = 0; i < 4; ++i)
        rw[i] = *reinterpret_cast<const float4*>(wsrc[i] + (size_t)(kt+1)*BK*N_COLS);
    }
    __syncthreads();
    bf16x8 ah[4], al[4], bh[4], bl[4];
    #pragma unroll
    for (int i = 0; i < 4; ++i){
      ah[i] = *reinterpret_cast<const bf16x8*>(&smem[aoff[i]]);
      al[i] = *reinterpret_cast<const bf16x8*>(&smem[SEC + aoff[i]]);
    }
    #pragma unroll
    for (int j = 0; j < 4; ++j){
      bh[j] = *reinterpret_cast<const bf16x8*>(&smem[2*SEC + boff[j]]);
      bl[j] = *reinterpret_cast<const bf16x8*>(&smem[3*SEC + boff[j]]);
    }
    #pragma unroll
    for (int i = 0; i < 4; ++i){
      #pragma unroll
      for (int j = 0; j < 4; ++j){
        acc[i][j] = __builtin_amdgcn_mfma_f32_16x16x32_bf16(ah[i], bh[j], acc[i][j], 0, 0, 0);
        acc[i][j] = __builtin_amdgcn_mfma_f32_16x16x32_bf16(al[i], bh[j], acc[i][j], 0, 0, 0);
        acc[i][j] = __builtin_amdgcn_mfma_f32_16x16x32_bf16(ah[i], bl[j], acc[i][j], 0, 0, 0);
      }
    }
  }

  float bvv[4];
  #pragma unroll
  for (int j = 0; j < 4; ++j) bvv[j] = bvec[n0 + wn*64 + j*16 + r];
  #pragma unroll
  for (int i = 0; i < 4; ++i){
    #pragma unroll
    for (int j = 0; j < 4; ++j){
      int col = n0 + wn*64 + j*16 + r;
      #pragma unroll
      for (int p = 0; p < 4; ++p){
        int row = m0 + wm*64 + i*16 + g*4 + p;
        out[(size_t)row * N_COLS + col] = cos_scaled(acc[i][j][p] + bvv[j]);
      }
    }
  }
}

extern "C" void kernel_launch(void* const* d_in, const int* in_sizes, int n_in,
                              void* d_out, int out_size, void* d_ws, size_t ws_size,
                              hipStream_t stream){
  const float* X = (const float*)d_in[0];
  const float* W = (const float*)d_in[1];
  const float* b = (const float*)d_in[2];
  float* out = (float*)d_out;
  unsigned short* ws = (unsigned short*)d_ws;

  const size_t needP = (APK_USHORTS + WPK_USHORTS) * sizeof(unsigned short); // 132 MiB

  if (ws && ws_size >= needP){
    unsigned short* Apk = ws;
    unsigned short* Wpk = ws + APK_USHORTS;
    pack_x<<<dim3(MB_CNT, NKT), 256, 0, stream>>>(X, Apk);
    pack_w<<<dim3(NB_CNT, NKT), 256, 0, stream>>>(W, Wpk);
    rbf_gemm_pk<<<8192, 256, 0, stream>>>(Apk, Wpk, b, out);
  } else {
    rbf_gemm_nows<<<8192, 256, 0, stream>>>(X, W, b, out);
  }
}

// Round 5
// 390.769 us; speedup vs baseline: 1.0757x; 1.0757x over previous
//
#include <hip/hip_runtime.h>

typedef __bf16 bf16x8 __attribute__((ext_vector_type(8)));
typedef float  f32x4  __attribute__((ext_vector_type(4)));

constexpr int M_ROWS = 65536;
constexpr int N_COLS = 2048;
constexpr int K_DIM  = 512;
constexpr int BM = 128, BN = 128, BK = 32;
constexpr int NKT = K_DIM / BK;        // 16 K-steps
constexpr int MB_CNT = M_ROWS / BM;    // 512
constexpr int NB_CNT = N_COLS / BN;    // 16

constexpr size_t A_ELEMS = (size_t)M_ROWS * K_DIM;
constexpr size_t W_ELEMS = (size_t)N_COLS * K_DIM;
// packed blocks: per (tile, kt): [hi 4096 ushorts][lo 4096 ushorts] = 16 KB
constexpr size_t APK_USHORTS = (size_t)MB_CNT * NKT * 8192;  // 128 MiB
constexpr size_t WPK_USHORTS = (size_t)NB_CNT * NKT * 8192;  //   4 MiB

__device__ __forceinline__ unsigned short f2bf(float f){
  unsigned int u = __float_as_uint(f);
  u += 0x7FFFu + ((u >> 16) & 1u);     // RNE
  return (unsigned short)(u >> 16);
}
__device__ __forceinline__ float bf2f(unsigned short h){
  return __uint_as_float(((unsigned int)h) << 16);
}
__device__ __forceinline__ void split4(const float4& v, ushort4& h, ushort4& l){
  h.x = f2bf(v.x); l.x = f2bf(v.x - bf2f(h.x));
  h.y = f2bf(v.y); l.y = f2bf(v.y - bf2f(h.y));
  h.z = f2bf(v.z); l.z = f2bf(v.z - bf2f(h.z));
  h.w = f2bf(v.w); l.w = f2bf(v.w - bf2f(h.w));
}
__device__ __forceinline__ void split4v(const f32x4& v, ushort4& h, ushort4& l){
  h.x = f2bf(v.x); l.x = f2bf(v.x - bf2f(h.x));
  h.y = f2bf(v.y); l.y = f2bf(v.y - bf2f(h.y));
  h.z = f2bf(v.z); l.z = f2bf(v.z - bf2f(h.z));
  h.w = f2bf(v.w); l.w = f2bf(v.w - bf2f(h.w));
}

__device__ __forceinline__ void gl_lds16(const void* g, void* l){
  __builtin_amdgcn_global_load_lds(
      (const __attribute__((address_space(1))) unsigned int*)g,
      (__attribute__((address_space(3))) unsigned int*)l, 16, 0, 0);
}

constexpr float INV2PI = 0.15915494309189535f;
__device__ __forceinline__ float cos_scaled(float v){
  float rev = v * INV2PI;
  rev -= floorf(rev);                   // [0,1) revolutions for v_cos
  return 0.03125f * __builtin_amdgcn_cosf(rev);
}

// ---------------- fused prepass: X->Apk (8192 blocks) + W->Wpk (1024) -------
// Apk block (mb,kt): chunk c = i*64 + q*16 + r  <->  A row mb*128+i*16+r,
// k = kt*32 + q*8..+7 (k-contiguous bf16). hi at +0, lo at +4096 ushorts.
// Wpk block (nb,kt): chunk c = s*64 + q*16 + fc holds W[k=kt*32+q*8..][n],
// n = nb*128 + (s>>2)*64 + fc*4 + (s&3)  (col-perm for float4 epilogue).
__global__ void pack_fused(const float* __restrict__ X, const float* __restrict__ W,
                           unsigned short* __restrict__ Apk,
                           unsigned short* __restrict__ Wpk){
  __shared__ __align__(16) unsigned short lds[8192];
  const int b = blockIdx.x, t = threadIdx.x;
  if (b < MB_CNT * NKT){
    const int mb = b >> 4, kt = b & 15;
    const float* src = X + (size_t)mb * 128 * K_DIM + kt * 32;
    const int fq = t & 7, r0 = t >> 3;
    #pragma unroll
    for (int it = 0; it < 4; ++it){
      int row = r0 + it * 32;
      f32x4 v = __builtin_nontemporal_load(
          reinterpret_cast<const f32x4*>(src + (size_t)row * K_DIM + fq * 4));
      ushort4 h, l; split4v(v, h, l);
      int i = row >> 4, r = row & 15, q = fq >> 1, half = fq & 1;
      int base = (i * 64 + q * 16 + r) * 8 + half * 4;
      *reinterpret_cast<ushort4*>(lds + base)        = h;
      *reinterpret_cast<ushort4*>(lds + 4096 + base) = l;
    }
    __syncthreads();
    unsigned short* dst = Apk + ((size_t)mb * NKT + kt) * 8192;
    #pragma unroll
    for (int it = 0; it < 4; ++it){
      int c = t + it * 256;
      *reinterpret_cast<int4*>(dst + c * 8) = *reinterpret_cast<const int4*>(lds + c * 8);
    }
  } else {
    const int b2 = b - MB_CNT * NKT;
    const int nbx = b2 & 63, kty = b2 >> 6;   // n0 = nbx*32, k0 = kty*32
    const int nq = t & 31, kr0 = t >> 5;
    const int nb = nbx >> 2;                  // which 128-col Wpk block
    const int kt = kty;
    #pragma unroll
    for (int it = 0; it < 4; ++it){
      int kr = kr0 + it * 8;
      float4 v = *reinterpret_cast<const float4*>(
          W + (size_t)(kt * 32 + kr) * N_COLS + nbx * 32 + nq);
      // note: nq in [0,32) covers 32 floats with float4? No — nq*1 would misalign.
      (void)v;
    }
    // --- (re-written cleanly below; see body) ---
    // Each block handles a 32-col x 32-k patch: n0 = nbx*32, k0 = kt*32.
    const int n0 = nbx * 32;
    float (*tf)[33] = reinterpret_cast<float(*)[33]>(lds);
    {
      int tx = t & 31, ty = t >> 5;
      #pragma unroll
      for (int rr = 0; rr < 4; ++rr)
        tf[ty + rr*8][tx] = W[(size_t)(kt * 32 + ty + rr*8) * N_COLS + n0 + tx];
      __syncthreads();
      #pragma unroll
      for (int rr = 0; rr < 4; ++rr){
        int nl = ty + rr*8;                     // local col 0..31
        float vv = tf[tx][nl];                  // W[k0+tx][n0+nl]
        unsigned short h = f2bf(vv);
        unsigned short l = f2bf(vv - bf2f(h));
        int ng = n0 + nl - nb * 128;            // col within 128-block
        int s  = ((ng >> 6) << 2) + (ng & 3);
        int fc = (ng >> 2) & 15;
        int q  = tx >> 3, ko = tx & 7;
        int e  = (s * 64 + q * 16 + fc) * 8 + ko;
        unsigned short* dst = Wpk + ((size_t)nb * NKT + kt) * 8192;
        dst[e] = h; dst[4096 + e] = l;
      }
    }
  }
}

// ---------------- main GEMM + cos epilogue ----------------------------------
// LDS 48 KB: Abuf0 [hi 8K|lo 8K] @0, Abuf1 @16K, Bbuf [hi 8K|lo 8K] @32K.
// Per K-step: ds_read frags -> bar1 -> issue gl_lds(kt+1) -> 48 MFMA -> bar2.
__launch_bounds__(256, 2)
__global__ void rbf_gemm_pk(const unsigned short* __restrict__ Apk,
                            const unsigned short* __restrict__ Wpk,
                            const float* __restrict__ bvec,
                            float* __restrict__ out){
  __shared__ __align__(16) unsigned short smem[24576];   // 48 KB

  int orig = blockIdx.x;                       // 8192 blocks, 8192 % 8 == 0
  int wgid = (orig & 7) * 1024 + (orig >> 3);  // bijective XCD swizzle
  int mb = wgid >> 4, nb = wgid & 15;
  int m0 = mb * BM, n0 = nb * BN;

  int tid = threadIdx.x, lane = tid & 63, wid = tid >> 6;
  int wm = wid >> 1, wn = wid & 1;
  int r = lane & 15, g = lane >> 4;

  const char* asrc = (const char*)(Apk + (size_t)mb * NKT * 8192) + tid * 16;
  const char* bsrc = (const char*)(Wpk + (size_t)nb * NKT * 8192) + tid * 16;
  char* ldsb = (char*)smem;
  const int ldst = wid * 1024;                 // per-wave dest offset per 4KB sec

  f32x4 acc[4][4];
  f32x4 zero = {0.f, 0.f, 0.f, 0.f};
  #pragma unroll
  for (int i = 0; i < 4; ++i)
    #pragma unroll
    for (int j = 0; j < 4; ++j) acc[i][j] = zero;

  const int lbase = lane * 8;                  // ushort offset of lane's chunk

  // prologue: stage tile 0 (A -> Abuf0, B -> Bbuf)
  #pragma unroll
  for (int it = 0; it < 4; ++it)
    gl_lds16(asrc + it * 4096, ldsb + it * 4096 + ldst);
  #pragma unroll
  for (int it = 0; it < 4; ++it)
    gl_lds16(bsrc + it * 4096, ldsb + 32768 + it * 4096 + ldst);
  __syncthreads();                             // drain: tile 0 ready

  #pragma unroll 1
  for (int kt = 0; kt < NKT; ++kt){
    const unsigned short* SA = smem + (kt & 1) * 8192;   // ushort idx
    const unsigned short* SB = smem + 16384;

    // 1) ds_read current-tile fragments
    bf16x8 ah[4], al[4], bh[4], bl[4];
    #pragma unroll
    for (int i = 0; i < 4; ++i){
      int o = (wm * 4 + i) * 512 + lbase;
      ah[i] = *reinterpret_cast<const bf16x8*>(&SA[o]);
      al[i] = *reinterpret_cast<const bf16x8*>(&SA[o + 4096]);
    }
    #pragma unroll
    for (int j = 0; j < 4; ++j){
      int o = (wn * 4 + j) * 512 + lbase;
      bh[j] = *reinterpret_cast<const bf16x8*>(&SB[o]);
      bl[j] = *reinterpret_cast<const bf16x8*>(&SB[o + 4096]);
    }
    __syncthreads();   // bar1: all waves' reads of Bbuf/Abuf done (lgkm drained)

    // 2) issue next-tile gl_lds EARLY (covered by the MFMA cluster below)
    if (kt + 1 < NKT){
      char* LA = ldsb + ((kt + 1) & 1) * 16384;          // byte offset
      const char* ab = asrc + (size_t)(kt + 1) * 16384;
      const char* bb = bsrc + (size_t)(kt + 1) * 16384;
      #pragma unroll
      for (int it = 0; it < 4; ++it) gl_lds16(ab + it * 4096, LA + it * 4096 + ldst);
      #pragma unroll
      for (int it = 0; it < 4; ++it) gl_lds16(bb + it * 4096, ldsb + 32768 + it * 4096 + ldst);
    }

    // 3) MFMA cluster
    #pragma unroll
    for (int i = 0; i < 4; ++i){
      #pragma unroll
      for (int j = 0; j < 4; ++j){
        acc[i][j] = __builtin_amdgcn_mfma_f32_16x16x32_bf16(ah[i], bh[j], acc[i][j], 0, 0, 0);
        acc[i][j] = __builtin_amdgcn_mfma_f32_16x16x32_bf16(al[i], bh[j], acc[i][j], 0, 0, 0);
        acc[i][j] = __builtin_amdgcn_mfma_f32_16x16x32_bf16(ah[i], bl[j], acc[i][j], 0, 0, 0);
      }
    }

    __syncthreads();   // bar2: vmcnt drain (covered) — next tile ready
  }

  // epilogue: col for acc[i][j] lane(r,g) reg p = n0 + wn*64 + r*4 + j
  //           row = m0 + wm*64 + i*16 + g*4 + p  -> nontemporal f32x4 stores
  int colb = n0 + wn * 64 + r * 4;
  float4 bv4 = *reinterpret_cast<const float4*>(bvec + colb);
  #pragma unroll
  for (int i = 0; i < 4; ++i){
    #pragma unroll
    for (int p = 0; p < 4; ++p){
      int row = m0 + wm * 64 + i * 16 + g * 4 + p;
      f32x4 o;
      o.x = cos_scaled(acc[i][0][p] + bv4.x);
      o.y = cos_scaled(acc[i][1][p] + bv4.y);
      o.z = cos_scaled(acc[i][2][p] + bv4.z);
      o.w = cos_scaled(acc[i][3][p] + bv4.w);
      __builtin_nontemporal_store(o, reinterpret_cast<f32x4*>(out + (size_t)row * N_COLS + colb));
    }
  }
}

// ---------------- fallback (no workspace) -----------------------------------
constexpr int LDSK = 40;
constexpr int SEC  = 128 * LDSK;
__launch_bounds__(256, 2)
__global__ void rbf_gemm_nows(const float* __restrict__ X, const float* __restrict__ W,
                              const float* __restrict__ bvec, float* __restrict__ out){
  __shared__ __align__(16) unsigned short smem[4 * SEC];
  int orig = blockIdx.x;
  int wgid = (orig & 7) * (int)(gridDim.x >> 3) + (orig >> 3);
  int mb = wgid >> 4, nb = wgid & 15;
  int m0 = mb * BM, n0 = nb * BN;
  int tid = threadIdx.x, lane = tid & 63, wid = tid >> 6;
  int wm = wid >> 1, wn = wid & 1;
  int r = lane & 15, g = lane >> 4;

  const float* asrc[4]; int alofs[4]; float4 ra[4];
  const float* wsrc[4]; int wnq4[4]; int wkr[4]; float4 rw[4];
  #pragma unroll
  for (int i = 0; i < 4; ++i){
    int c = tid + i * 256;
    int row = c >> 3, q = c & 7;
    asrc[i]  = X + (size_t)(m0 + row) * K_DIM + q * 4;
    alofs[i] = row * LDSK + q * 4;
  }
  #pragma unroll
  for (int i = 0; i < 4; ++i) ra[i] = *reinterpret_cast<const float4*>(asrc[i]);
  #pragma unroll
  for (int i = 0; i < 4; ++i){
    int c = tid + i * 256;
    int kr = c >> 5, nq = c & 31;
    wsrc[i] = W + (size_t)kr * N_COLS + n0 + nq * 4;
    wkr[i] = kr; wnq4[i] = nq * 4;
  }
  #pragma unroll
  for (int i = 0; i < 4; ++i) rw[i] = *reinterpret_cast<const float4*>(wsrc[i]);

  f32x4 acc[4][4];
  f32x4 zero = {0.f, 0.f, 0.f, 0.f};
  #pragma unroll
  for (int i = 0; i < 4; ++i)
    #pragma unroll
    for (int j = 0; j < 4; ++j) acc[i][j] = zero;

  int aoff[4], boff[4];
  #pragma unroll
  for (int i = 0; i < 4; ++i) aoff[i] = (wm*64 + i*16 + r) * LDSK + g * 8;
  #pragma unroll
  for (int j = 0; j < 4; ++j) boff[j] = (wn*64 + j*16 + r) * LDSK + g * 8;

  #pragma unroll 1
  for (int kt = 0; kt < NKT; ++kt){
    __syncthreads();
    #pragma unroll
    for (int i = 0; i < 4; ++i){
      ushort4 h, l;
      split4(ra[i], h, l);
      *reinterpret_cast<ushort4*>(&smem[alofs[i]])       = h;
      *reinterpret_cast<ushort4*>(&smem[SEC + alofs[i]]) = l;
    }
    #pragma unroll
    for (int i = 0; i < 4; ++i){
      float vv[4] = {rw[i].x, rw[i].y, rw[i].z, rw[i].w};
      #pragma unroll
      for (int w2 = 0; w2 < 4; ++w2){
        unsigned short h = f2bf(vv[w2]);
        unsigned short l = f2bf(vv[w2] - bf2f(h));
        int n = wnq4[i] + w2;
        smem[2*SEC + n*LDSK + wkr[i]] = h;
        smem[3*SEC + n*LDSK + wkr[i]] = l;
      }
    }
    if (kt < NKT - 1){
      #pragma unroll
      for (int i = 0; i < 4; ++i)
        ra[i] = *reinterpret_cast<const float4*>(asrc[i] + (kt+1)*BK);
      #pragma unroll
      for (int i = 0; i < 4; ++i)
        rw[i] = *reinterpret_cast<const float4*>(wsrc[i] + (size_t)(kt+1)*BK*N_COLS);
    }
    __syncthreads();
    bf16x8 ah[4], al[4], bh[4], bl[4];
    #pragma unroll
    for (int i = 0; i < 4; ++i){
      ah[i] = *reinterpret_cast<const bf16x8*>(&smem[aoff[i]]);
      al[i] = *reinterpret_cast<const bf16x8*>(&smem[SEC + aoff[i]]);
    }
    #pragma unroll
    for (int j = 0; j < 4; ++j){
      bh[j] = *reinterpret_cast<const bf16x8*>(&smem[2*SEC + boff[j]]);
      bl[j] = *reinterpret_cast<const bf16x8*>(&smem[3*SEC + boff[j]]);
    }
    #pragma unroll
    for (int i = 0; i < 4; ++i){
      #pragma unroll
      for (int j = 0; j < 4; ++j){
        acc[i][j] = __builtin_amdgcn_mfma_f32_16x16x32_bf16(ah[i], bh[j], acc[i][j], 0, 0, 0);
        acc[i][j] = __builtin_amdgcn_mfma_f32_16x16x32_bf16(al[i], bh[j], acc[i][j], 0, 0, 0);
        acc[i][j] = __builtin_amdgcn_mfma_f32_16x16x32_bf16(ah[i], bl[j], acc[i][j], 0, 0, 0);
      }
    }
  }

  float bvv[4];
  #pragma unroll
  for (int j = 0; j < 4; ++j) bvv[j] = bvec[n0 + wn*64 + j*16 + r];
  #pragma unroll
  for (int i = 0; i < 4; ++i){
    #pragma unroll
    for (int j = 0; j < 4; ++j){
      int col = n0 + wn*64 + j*16 + r;
      #pragma unroll
      for (int p = 0; p < 4; ++p){
        int row = m0 + wm*64 + i*16 + g*4 + p;
        out[(size_t)row * N_COLS + col] = cos_scaled(acc[i][j][p] + bvv[j]);
      }
    }
  }
}

extern "C" void kernel_launch(void* const* d_in, const int* in_sizes, int n_in,
                              void* d_out, int out_size, void* d_ws, size_t ws_size,
                              hipStream_t stream){
  const float* X = (const float*)d_in[0];
  const float* W = (const float*)d_in[1];
  const float* b = (const float*)d_in[2];
  float* out = (float*)d_out;
  unsigned short* ws = (unsigned short*)d_ws;

  const size_t needP = (APK_USHORTS + WPK_USHORTS) * sizeof(unsigned short); // 132 MiB

  if (ws && ws_size >= needP){
    unsigned short* Apk = ws;
    unsigned short* Wpk = ws + APK_USHORTS;
    pack_fused<<<MB_CNT * NKT + 64 * NKT, 256, 0, stream>>>(X, W, Apk, Wpk);
    rbf_gemm_pk<<<8192, 256, 0, stream>>>(Apk, Wpk, b, out);
  } else {
    rbf_gemm_nows<<<8192, 256, 0, stream>>>(X, W, b, out);
  }
}